// Round 1
// baseline (5530.474 us; speedup 1.0000x reference)
//
#include <hip/hip_runtime.h>
#include <hip/hip_bf16.h>

// Bidirectional Elman RNN: B=32, S=2048, D=256, H=256.
// Kernel 1 (proj): xp = x @ [Wx_f | Wx_b] + [b_f | b_b]  -> written into d_out [B*S, 512]
//   bf16 MFMA 16x16x32, 128x128 block tile, K-chunk 32.
// Kernel 2 (scan): 64 workgroups (32 batches x 2 dirs), one recurrent chain each.
//   Thread j holds Wh[:,j] (256 fp32) in VGPRs; h in LDS; xp read from d_out and
//   overwritten with h in place.

#define SEQ 2048
#define BATCH 32
#define HDIM 256

typedef __attribute__((ext_vector_type(8))) short short8;
typedef __attribute__((ext_vector_type(4))) short short4_;
typedef __attribute__((ext_vector_type(4))) float f32x4;

__device__ inline short f2bf(float x) {
    unsigned u = __builtin_bit_cast(unsigned, x);
    u += 0x7fffu + ((u >> 16) & 1u);   // RNE; inputs are finite
    return (short)(u >> 16);
}

// ---------------- Kernel 1: input projection (bf16 MFMA) ----------------
// grid: (4, 512)  block: 256. Block tile: 128(M) x 128(N); N-tile entirely in one dir.
__global__ __launch_bounds__(256) void proj_kernel(
    const float* __restrict__ X,    // [65536][256]
    const float* __restrict__ Wf,   // [256][256]
    const float* __restrict__ bfv,  // [256]
    const float* __restrict__ Wb,   // [256][256]
    const float* __restrict__ bbv,  // [256]
    float* __restrict__ out)        // [65536][512]
{
    __shared__ __align__(16) short As[128 * 40];      // [m][k], row pad 40 (80B, 16B-mult)
    __shared__ __align__(16) short Bs[4 * 128 * 8];   // k8-packed: [k>>3][n][k&7]

    const int tid  = threadIdx.x;
    const int m0   = blockIdx.y * 128;
    const int n0   = blockIdx.x * 128;
    const float* W    = (n0 < 256) ? Wf  : Wb;
    const float* bias = (n0 < 256) ? bfv : bbv;
    const int nb = n0 & 255;

    const int wid  = tid >> 6;
    const int lane = tid & 63;
    const int l16  = lane & 15;
    const int quad = lane >> 4;
    const int wm   = (wid & 1) * 64;
    const int wn   = (wid >> 1) * 64;

    f32x4 acc[4][4] = {};

    for (int kc = 0; kc < 256; kc += 32) {
        __syncthreads();
        // stage A tile: 128x32 fp32 -> bf16 LDS
        #pragma unroll
        for (int i = 0; i < 4; i++) {
            int e   = tid + i * 256;           // float4 id, 1024 total (128 rows x 8)
            int row = e >> 3, c4 = e & 7;
            float4 v = *(const float4*)(X + (size_t)(m0 + row) * 256 + kc + c4 * 4);
            short4_ sv;
            sv.x = f2bf(v.x); sv.y = f2bf(v.y); sv.z = f2bf(v.z); sv.w = f2bf(v.w);
            *(short4_*)&As[row * 40 + c4 * 4] = sv;
        }
        // stage B tile: 32x128 fp32 -> bf16 LDS (k8-packed so frag reads are contiguous)
        #pragma unroll
        for (int i = 0; i < 4; i++) {
            int e  = tid + i * 256;            // float4 id, 1024 total (32 rows x 32)
            int k  = e >> 5, c4 = e & 31;
            float4 v = *(const float4*)(W + (size_t)(kc + k) * 256 + nb + c4 * 4);
            short* dst = &Bs[(k >> 3) * 1024 + (c4 * 4) * 8 + (k & 7)];
            dst[0]  = f2bf(v.x);
            dst[8]  = f2bf(v.y);
            dst[16] = f2bf(v.z);
            dst[24] = f2bf(v.w);
        }
        __syncthreads();

        short8 afr[4], bfr[4];
        #pragma unroll
        for (int mi = 0; mi < 4; mi++)
            afr[mi] = *(const short8*)&As[(wm + mi * 16 + l16) * 40 + quad * 8];
        #pragma unroll
        for (int ni = 0; ni < 4; ni++)
            bfr[ni] = *(const short8*)&Bs[quad * 1024 + (wn + ni * 16 + l16) * 8];
        #pragma unroll
        for (int mi = 0; mi < 4; mi++)
            #pragma unroll
            for (int ni = 0; ni < 4; ni++)
                acc[mi][ni] = __builtin_amdgcn_mfma_f32_16x16x32_bf16(
                    afr[mi], bfr[ni], acc[mi][ni], 0, 0, 0);
    }

    // epilogue: D[row][col]: col = lane&15, row = quad*4 + reg  (+ bias)
    #pragma unroll
    for (int ni = 0; ni < 4; ni++) {
        int col = n0 + wn + ni * 16 + l16;
        float bv = bias[col & 255];
        #pragma unroll
        for (int mi = 0; mi < 4; mi++) {
            #pragma unroll
            for (int r = 0; r < 4; r++) {
                int row = m0 + wm + mi * 16 + quad * 4 + r;
                out[(size_t)row * 512 + col] = acc[mi][ni][r] + bv;
            }
        }
    }
}

// ---------------- Kernel 2: sequential scan ----------------
// grid: 64 (b = bid&31, dir = bid>>5), block: 256. Thread j owns output neuron j.
__global__ __launch_bounds__(256, 1) void scan_kernel(
    const float* __restrict__ Whf,  // [256][256]
    const float* __restrict__ Whb,  // [256][256]
    float* __restrict__ out)        // [B*S][512]; holds xp, overwritten with h
{
    __shared__ float h[HDIM];
    const int j   = threadIdx.x;
    const int b   = blockIdx.x & 31;
    const int dir = blockIdx.x >> 5;
    const float* Wh = dir ? Whb : Whf;

    // preload Wh[:,j] into registers (coalesced across j)
    f32x4 w[64];
    #pragma unroll
    for (int kk = 0; kk < 64; kk++) {
        w[kk].x = Wh[(kk * 4 + 0) * 256 + j];
        w[kk].y = Wh[(kk * 4 + 1) * 256 + j];
        w[kk].z = Wh[(kk * 4 + 2) * 256 + j];
        w[kk].w = Wh[(kk * 4 + 3) * 256 + j];
    }

    h[j] = 0.f;
    __syncthreads();

    const long d = dir ? -512L : 512L;
    float* p = out + ((size_t)b * SEQ + (dir ? SEQ - 1 : 0)) * 512 + dir * 256 + j;
    float xp_cur = *p;

    for (int s = 0; s < SEQ; s++) {
        float xp_next = (s + 1 < SEQ) ? p[d] : 0.f;   // prefetch next step's xp
        float acc = xp_cur;
        const f32x4* h4 = (const f32x4*)h;
        #pragma unroll
        for (int kk = 0; kk < 64; kk++) {
            f32x4 hv = h4[kk];                         // ds_read_b128 broadcast
            acc += hv.x * w[kk].x;
            acc += hv.y * w[kk].y;
            acc += hv.z * w[kk].z;
            acc += hv.w * w[kk].w;
        }
        // tanh(acc)
        float t = __expf(-2.f * fabsf(acc));
        float r = (1.f - t) / (1.f + t);
        r = copysignf(r, acc);

        __syncthreads();        // everyone done reading h
        h[j] = r;
        *p = r;                 // overwrite xp with output h
        __syncthreads();        // h ready for next step
        p += d;
        xp_cur = xp_next;
    }
}

extern "C" void kernel_launch(void* const* d_in, const int* in_sizes, int n_in,
                              void* d_out, int out_size, void* d_ws, size_t ws_size,
                              hipStream_t stream) {
    const float* X    = (const float*)d_in[0];
    const float* Wx_f = (const float*)d_in[1];
    const float* Wh_f = (const float*)d_in[2];
    const float* b_f  = (const float*)d_in[3];
    const float* Wx_b = (const float*)d_in[4];
    const float* Wh_b = (const float*)d_in[5];
    const float* b_b  = (const float*)d_in[6];
    float* out = (float*)d_out;

    dim3 pgrid(4, 512);
    proj_kernel<<<pgrid, 256, 0, stream>>>(X, Wx_f, b_f, Wx_b, b_b, out);
    scan_kernel<<<64, 256, 0, stream>>>(Wh_f, Wh_b, out);
}

// Round 2
// 2353.165 us; speedup vs baseline: 2.3502x; 2.3502x over previous
//
#include <hip/hip_runtime.h>
#include <hip/hip_bf16.h>

// Bidirectional Elman RNN: B=32, S=2048, D=256, H=256.
// Kernel 1 (proj): xp = x @ [Wx_f | Wx_b] + [b_f | b_b]  -> written into d_out [B*S, 512]
// Kernel 2 (scan): 64 workgroups (32 batches x 2 dirs), one recurrent chain each.
//   512 threads: 2 threads per neuron (p = t&1 takes k-half), pair-sum via shfl_xor.
//   h double-buffered in LDS -> ONE raw barrier per step (lgkmcnt only; global
//   prefetch/store stay in flight across it).

#define SEQ 2048
#define BATCH 32
#define HDIM 256

typedef __attribute__((ext_vector_type(8))) short short8;
typedef __attribute__((ext_vector_type(4))) short short4_;
typedef __attribute__((ext_vector_type(4))) float f32x4;

__device__ inline short f2bf(float x) {
    unsigned u = __builtin_bit_cast(unsigned, x);
    u += 0x7fffu + ((u >> 16) & 1u);   // RNE; inputs are finite
    return (short)(u >> 16);
}

// ---------------- Kernel 1: input projection (bf16 MFMA) ----------------
// grid: (4, 512)  block: 256. Block tile: 128(M) x 128(N); N-tile entirely in one dir.
__global__ __launch_bounds__(256) void proj_kernel(
    const float* __restrict__ X,    // [65536][256]
    const float* __restrict__ Wf,   // [256][256]
    const float* __restrict__ bfv,  // [256]
    const float* __restrict__ Wb,   // [256][256]
    const float* __restrict__ bbv,  // [256]
    float* __restrict__ out)        // [65536][512]
{
    __shared__ __align__(16) short As[128 * 40];      // [m][k], row pad 40 (80B, 16B-mult)
    __shared__ __align__(16) short Bs[4 * 128 * 8];   // k8-packed: [k>>3][n][k&7]

    const int tid  = threadIdx.x;
    const int m0   = blockIdx.y * 128;
    const int n0   = blockIdx.x * 128;
    const float* W    = (n0 < 256) ? Wf  : Wb;
    const float* bias = (n0 < 256) ? bfv : bbv;
    const int nb = n0 & 255;

    const int wid  = tid >> 6;
    const int lane = tid & 63;
    const int l16  = lane & 15;
    const int quad = lane >> 4;
    const int wm   = (wid & 1) * 64;
    const int wn   = (wid >> 1) * 64;

    f32x4 acc[4][4] = {};

    for (int kc = 0; kc < 256; kc += 32) {
        __syncthreads();
        // stage A tile: 128x32 fp32 -> bf16 LDS
        #pragma unroll
        for (int i = 0; i < 4; i++) {
            int e   = tid + i * 256;           // float4 id, 1024 total (128 rows x 8)
            int row = e >> 3, c4 = e & 7;
            float4 v = *(const float4*)(X + (size_t)(m0 + row) * 256 + kc + c4 * 4);
            short4_ sv;
            sv.x = f2bf(v.x); sv.y = f2bf(v.y); sv.z = f2bf(v.z); sv.w = f2bf(v.w);
            *(short4_*)&As[row * 40 + c4 * 4] = sv;
        }
        // stage B tile: 32x128 fp32 -> bf16 LDS (k8-packed so frag reads are contiguous)
        #pragma unroll
        for (int i = 0; i < 4; i++) {
            int e  = tid + i * 256;            // float4 id, 1024 total (32 rows x 32)
            int k  = e >> 5, c4 = e & 31;
            float4 v = *(const float4*)(W + (size_t)(kc + k) * 256 + nb + c4 * 4);
            short* dst = &Bs[(k >> 3) * 1024 + (c4 * 4) * 8 + (k & 7)];
            dst[0]  = f2bf(v.x);
            dst[8]  = f2bf(v.y);
            dst[16] = f2bf(v.z);
            dst[24] = f2bf(v.w);
        }
        __syncthreads();

        short8 afr[4], bfr[4];
        #pragma unroll
        for (int mi = 0; mi < 4; mi++)
            afr[mi] = *(const short8*)&As[(wm + mi * 16 + l16) * 40 + quad * 8];
        #pragma unroll
        for (int ni = 0; ni < 4; ni++)
            bfr[ni] = *(const short8*)&Bs[quad * 1024 + (wn + ni * 16 + l16) * 8];
        #pragma unroll
        for (int mi = 0; mi < 4; mi++)
            #pragma unroll
            for (int ni = 0; ni < 4; ni++)
                acc[mi][ni] = __builtin_amdgcn_mfma_f32_16x16x32_bf16(
                    afr[mi], bfr[ni], acc[mi][ni], 0, 0, 0);
    }

    // epilogue: D[row][col]: col = lane&15, row = quad*4 + reg  (+ bias)
    #pragma unroll
    for (int ni = 0; ni < 4; ni++) {
        int col = n0 + wn + ni * 16 + l16;
        float bv = bias[col & 255];
        #pragma unroll
        for (int mi = 0; mi < 4; mi++) {
            #pragma unroll
            for (int r = 0; r < 4; r++) {
                int row = m0 + wm + mi * 16 + quad * 4 + r;
                out[(size_t)row * 512 + col] = acc[mi][ni][r] + bv;
            }
        }
    }
}

// ---------------- Kernel 2: sequential scan ----------------
// grid: 64 (b = bid&31, dir = bid>>5), block: 512.
// Thread t: neuron j = t>>1, k-half p = t&1. Each thread holds Wh[p*128..+127, j]
// (32 f32x4) in VGPRs. h double-buffered in LDS; one raw barrier per step.
__global__ __launch_bounds__(512, 2) void scan_kernel(
    const float* __restrict__ Whf,  // [256][256]
    const float* __restrict__ Whb,  // [256][256]
    float* __restrict__ out)        // [B*S][512]; holds xp, overwritten with h
{
    __shared__ __align__(16) float h[2][HDIM];
    const int t   = threadIdx.x;
    const int j   = t >> 1;
    const int p   = t & 1;
    const int b   = blockIdx.x & 31;
    const int dir = blockIdx.x >> 5;
    const float* Wh = dir ? Whb : Whf;

    // preload this thread's half-column of Wh into registers
    f32x4 w[32];
    #pragma unroll
    for (int kk = 0; kk < 32; kk++) {
        int k0 = p * 128 + kk * 4;
        w[kk].x = Wh[(k0 + 0) * 256 + j];
        w[kk].y = Wh[(k0 + 1) * 256 + j];
        w[kk].z = Wh[(k0 + 2) * 256 + j];
        w[kk].w = Wh[(k0 + 3) * 256 + j];
    }

    if (t < HDIM) h[0][t] = 0.f;
    __syncthreads();

    const long d = dir ? -512L : 512L;
    float* ptr = out + ((size_t)b * SEQ + (dir ? SEQ - 1 : 0)) * 512 + dir * 256 + j;
    float xp_cur = *ptr;   // both lanes of a pair load the same address

    int rb = 0;
    for (int s = 0; s < SEQ; s++) {
        float xp_next = (s + 1 < SEQ) ? ptr[d] : 0.f;   // stays in flight across barrier
        const f32x4* h4 = (const f32x4*)&h[rb][p * 128];
        float a0 = 0.f, a1 = 0.f;
        #pragma unroll
        for (int kk = 0; kk < 32; kk += 2) {
            f32x4 h0 = h4[kk];
            f32x4 h1 = h4[kk + 1];
            a0 += h0.x * w[kk].x;
            a0 += h0.y * w[kk].y;
            a0 += h0.z * w[kk].z;
            a0 += h0.w * w[kk].w;
            a1 += h1.x * w[kk + 1].x;
            a1 += h1.y * w[kk + 1].y;
            a1 += h1.z * w[kk + 1].z;
            a1 += h1.w * w[kk + 1].w;
        }
        float acc = a0 + a1;
        acc += __shfl_xor(acc, 1);   // pair sum: both lanes now hold full dot
        acc += xp_cur;
        // tanh via exp2-based expf + fast rcp (precision ~1 ulp rcp, fine vs 2e-2)
        float tt = __expf(-2.f * fabsf(acc));
        float r = (1.f - tt) * __builtin_amdgcn_rcpf(1.f + tt);
        r = copysignf(r, acc);

        if (p == 0) {
            h[rb ^ 1][j] = r;   // write NEXT buffer (no WAR on current)
            *ptr = r;           // overwrite xp with output h (fire-and-forget)
        }
        // raw barrier: drain LDS only; global prefetch/store stay outstanding
        asm volatile("s_waitcnt lgkmcnt(0)\n\ts_barrier" ::: "memory");

        rb ^= 1;
        ptr += d;
        xp_cur = xp_next;
    }
}

extern "C" void kernel_launch(void* const* d_in, const int* in_sizes, int n_in,
                              void* d_out, int out_size, void* d_ws, size_t ws_size,
                              hipStream_t stream) {
    const float* X    = (const float*)d_in[0];
    const float* Wx_f = (const float*)d_in[1];
    const float* Wh_f = (const float*)d_in[2];
    const float* b_f  = (const float*)d_in[3];
    const float* Wx_b = (const float*)d_in[4];
    const float* Wh_b = (const float*)d_in[5];
    const float* b_b  = (const float*)d_in[6];
    float* out = (float*)d_out;

    dim3 pgrid(4, 512);
    proj_kernel<<<pgrid, 256, 0, stream>>>(X, Wx_f, b_f, Wx_b, b_b, out);
    scan_kernel<<<64, 512, 0, stream>>>(Wh_f, Wh_b, out);
}